// Round 1
// baseline (449.002 us; speedup 1.0000x reference)
//
#include <hip/hip_runtime.h>

// GCN layer: agg = segment_sum(feats[src], dst); h = relu(agg@W+b) + relu(feats@Wr+br);
// out = batchnorm(h) over node dim (biased var, eps=1e-5), * gamma + beta.
// All fp32. N=100000 nodes, E=1600000 edges, F=64.

constexpr int MV_BLOCKS = 1024;

// ---------------- scatter: agg[dst[e]] += feats[src[e]] ----------------
// one wave (64 lanes) per edge, lane = feature index
__global__ __launch_bounds__(256) void k_scatter(
    const float* __restrict__ feats, const int* __restrict__ src,
    const int* __restrict__ dst, float* __restrict__ agg, int n_edges)
{
    const int lane = threadIdx.x & 63;
    long long gid = (long long)blockIdx.x * blockDim.x + threadIdx.x;
    int e = (int)(gid >> 6);
    if (e >= n_edges) return;
    e = __builtin_amdgcn_readfirstlane(e);     // wave-uniform -> scalar loads
    const int s = src[e];
    const int d = dst[e];
    const float v = feats[(size_t)s * 64 + lane];
    atomicAdd(agg + (size_t)d * 64 + lane, v);
}

// ------------- fused linear + relu + residual + BN partial sums -------------
// one wave per node; lane = output feature. W/Wr staged in LDS.
__global__ __launch_bounds__(256) void k_matvec(
    const float* __restrict__ agg, const float* __restrict__ feats,
    const float* __restrict__ W, const float* __restrict__ b,
    const float* __restrict__ Wr, const float* __restrict__ br,
    float* __restrict__ h, float* __restrict__ partials, int n_nodes)
{
    __shared__ float sW[64 * 64];
    __shared__ float sWr[64 * 64];
    __shared__ float sb[64];
    __shared__ float sbr[64];
    __shared__ float srow[4][2][64];
    __shared__ float ssum[128];

    for (int i = threadIdx.x; i < 4096; i += 256) { sW[i] = W[i]; sWr[i] = Wr[i]; }
    if (threadIdx.x < 64)  { sb[threadIdx.x] = b[threadIdx.x]; sbr[threadIdx.x] = br[threadIdx.x]; }
    if (threadIdx.x < 128) ssum[threadIdx.x] = 0.f;
    __syncthreads();

    const int wave = threadIdx.x >> 6;
    const int lane = threadIdx.x & 63;
    float lsum = 0.f, lsq = 0.f;

    for (int n = blockIdx.x * 4 + wave; n < n_nodes; n += MV_BLOCKS * 4) {
        srow[wave][0][lane] = agg[(size_t)n * 64 + lane];
        srow[wave][1][lane] = feats[(size_t)n * 64 + lane];
        // same-wave ds_write->ds_read: compiler inserts lgkmcnt wait; no cross-wave sharing
        float acc1 = sb[lane];
        float acc2 = sbr[lane];
        #pragma unroll
        for (int i0 = 0; i0 < 64; i0 += 4) {
            float4 a4 = *(const float4*)&srow[wave][0][i0];   // broadcast b128
            float4 f4 = *(const float4*)&srow[wave][1][i0];
            acc1 += a4.x * sW [(i0 + 0) * 64 + lane];  acc2 += f4.x * sWr[(i0 + 0) * 64 + lane];
            acc1 += a4.y * sW [(i0 + 1) * 64 + lane];  acc2 += f4.y * sWr[(i0 + 1) * 64 + lane];
            acc1 += a4.z * sW [(i0 + 2) * 64 + lane];  acc2 += f4.z * sWr[(i0 + 2) * 64 + lane];
            acc1 += a4.w * sW [(i0 + 3) * 64 + lane];  acc2 += f4.w * sWr[(i0 + 3) * 64 + lane];
        }
        float hv = fmaxf(acc1, 0.f) + fmaxf(acc2, 0.f);
        h[(size_t)n * 64 + lane] = hv;
        lsum += hv;
        lsq  += hv * hv;
    }

    atomicAdd(&ssum[lane], lsum);        // LDS atomics, 4 waves -> 128 slots
    atomicAdd(&ssum[64 + lane], lsq);
    __syncthreads();
    if (threadIdx.x < 128)
        partials[(size_t)blockIdx.x * 128 + threadIdx.x] = ssum[threadIdx.x];
}

// ---------------- BN stats finalize: scale/shift per feature ----------------
__global__ __launch_bounds__(128) void k_bnstats(
    const float* __restrict__ partials, const float* __restrict__ gamma,
    const float* __restrict__ beta, float* __restrict__ scaleshift, int n_nodes)
{
    const int t = threadIdx.x;   // 0..127
    float s = 0.f;
    for (int blk = 0; blk < MV_BLOCKS; blk++) s += partials[(size_t)blk * 128 + t];
    __shared__ float red[128];
    red[t] = s;
    __syncthreads();
    if (t < 64) {
        float mean = red[t] / (float)n_nodes;
        float var  = red[64 + t] / (float)n_nodes - mean * mean;  // biased
        float sc = gamma[t] * rsqrtf(var + 1e-5f);
        scaleshift[t]      = sc;
        scaleshift[64 + t] = beta[t] - mean * sc;
    }
}

// ---------------- BN apply (in-place on d_out) ----------------
__global__ __launch_bounds__(256) void k_bnapply(
    float* __restrict__ h, const float* __restrict__ scaleshift, int total4)
{
    __shared__ float ssc[64], ssh[64];
    if (threadIdx.x < 64) {
        ssc[threadIdx.x] = scaleshift[threadIdx.x];
        ssh[threadIdx.x] = scaleshift[64 + threadIdx.x];
    }
    __syncthreads();
    for (int i = blockIdx.x * blockDim.x + threadIdx.x; i < total4;
         i += gridDim.x * blockDim.x) {
        float4 v = ((float4*)h)[i];
        const int j = (i & 15) << 2;   // 16 float4 per 64-feat row
        v.x = v.x * ssc[j + 0] + ssh[j + 0];
        v.y = v.y * ssc[j + 1] + ssh[j + 1];
        v.z = v.z * ssc[j + 2] + ssh[j + 2];
        v.w = v.w * ssc[j + 3] + ssh[j + 3];
        ((float4*)h)[i] = v;
    }
}

extern "C" void kernel_launch(void* const* d_in, const int* in_sizes, int n_in,
                              void* d_out, int out_size, void* d_ws, size_t ws_size,
                              hipStream_t stream)
{
    const float* feats = (const float*)d_in[0];
    const int*   src   = (const int*)  d_in[1];
    const int*   dst   = (const int*)  d_in[2];
    const float* W     = (const float*)d_in[3];
    const float* b     = (const float*)d_in[4];
    const float* Wr    = (const float*)d_in[5];
    const float* br    = (const float*)d_in[6];
    const float* gamma = (const float*)d_in[7];
    const float* beta  = (const float*)d_in[8];

    const int n_nodes = in_sizes[0] / 64;
    const int n_edges = in_sizes[1];

    // workspace layout (fp32): agg[N*64] | partials[MV_BLOCKS*128] | scaleshift[128]
    float* agg        = (float*)d_ws;
    float* partials   = agg + (size_t)n_nodes * 64;
    float* scaleshift = partials + (size_t)MV_BLOCKS * 128;
    float* h          = (float*)d_out;

    hipMemsetAsync(agg, 0, (size_t)n_nodes * 64 * sizeof(float), stream);

    {
        long long threads = (long long)n_edges * 64;
        int blocks = (int)((threads + 255) / 256);
        k_scatter<<<blocks, 256, 0, stream>>>(feats, src, dst, agg, n_edges);
    }
    k_matvec<<<MV_BLOCKS, 256, 0, stream>>>(agg, feats, W, b, Wr, br, h, partials, n_nodes);
    k_bnstats<<<1, 128, 0, stream>>>(partials, gamma, beta, scaleshift, n_nodes);
    {
        const int total4 = n_nodes * 16;   // N*64/4
        k_bnapply<<<2048, 256, 0, stream>>>(h, scaleshift, total4);
    }
}

// Round 2
// 389.676 us; speedup vs baseline: 1.1522x; 1.1522x over previous
//
#include <hip/hip_runtime.h>

// GCN layer: agg = segment_sum(feats[src], dst); h = relu(agg@W+b) + relu(feats@Wr+br);
// out = batchnorm(h) over node dim (biased var, eps=1e-5) * gamma + beta.
// All fp32. N=100000 nodes, E=1600000 edges, F=64.
//
// R2: atomic scatter (355us, at the L2 atomic-op roofline ~290G/s) replaced by
// counting-sort CSR build + fused per-node gather/linear/BN-partial kernel.

constexpr int MV_BLOCKS = 1024;

// ---- pass 1: histogram of dst (int atomics, no return -> fast) ----
__global__ __launch_bounds__(256) void k_hist(const int* __restrict__ dst,
                                              int* __restrict__ cnt, int n_edges)
{
    for (int e = blockIdx.x * blockDim.x + threadIdx.x; e < n_edges;
         e += gridDim.x * blockDim.x)
        atomicAdd(&cnt[dst[e]], 1);
}

// ---- pass 2a: per-block (256-wide) scan; writes exclusive partials + block sum ----
__global__ __launch_bounds__(256) void k_scan1(const int* __restrict__ cnt,
                                               int* __restrict__ offs,
                                               int* __restrict__ bsum, int n)
{
    __shared__ int s[256];
    const int t = threadIdx.x;
    const int gid = blockIdx.x * 256 + t;
    int v = (gid < n) ? cnt[gid] : 0;
    s[t] = v;
    __syncthreads();
    for (int off = 1; off < 256; off <<= 1) {
        int x = (t >= off) ? s[t - off] : 0;
        __syncthreads();
        if (t >= off) s[t] += x;
        __syncthreads();
    }
    if (gid < n) offs[gid] = s[t] - v;          // exclusive within block
    if (t == 255) bsum[blockIdx.x] = s[255];    // block total
}

// ---- pass 2b: scan of block sums (one block; nb <= 512) ----
__global__ __launch_bounds__(512) void k_scan2(int* __restrict__ bsum, int nb)
{
    __shared__ int s[512];
    const int t = threadIdx.x;
    int v = (t < nb) ? bsum[t] : 0;
    s[t] = v;
    __syncthreads();
    for (int off = 1; off < 512; off <<= 1) {
        int x = (t >= off) ? s[t - off] : 0;
        __syncthreads();
        if (t >= off) s[t] += x;
        __syncthreads();
    }
    if (t < nb) bsum[t] = s[t] - v;             // exclusive, in place
}

// ---- pass 2c: add block offsets; init cursor; write offs[n] ----
__global__ __launch_bounds__(256) void k_scan3(int* __restrict__ offs,
                                               const int* __restrict__ bsum,
                                               int* __restrict__ cursor,
                                               int n, int n_edges)
{
    const int gid = blockIdx.x * 256 + threadIdx.x;
    if (gid < n) {
        int o = offs[gid] + bsum[blockIdx.x];
        offs[gid] = o;
        cursor[gid] = o;
    }
    if (gid == n) offs[n] = n_edges;
}

// ---- pass 3: bucket edges by dst (CSR build) ----
__global__ __launch_bounds__(256) void k_build(const int* __restrict__ src,
                                               const int* __restrict__ dst,
                                               int* __restrict__ cursor,
                                               int* __restrict__ sorted_src, int n_edges)
{
    for (int e = blockIdx.x * blockDim.x + threadIdx.x; e < n_edges;
         e += gridDim.x * blockDim.x) {
        int pos = atomicAdd(&cursor[dst[e]], 1);
        sorted_src[pos] = src[e];
    }
}

// ---- pass 4: fused gather-sum + linear + relu + residual + BN partials ----
// one wave per node; lane = feature index.
__global__ __launch_bounds__(256) void k_gather_mv(
    const float* __restrict__ feats, const int* __restrict__ offs,
    const int* __restrict__ sorted_src,
    const float* __restrict__ W, const float* __restrict__ b,
    const float* __restrict__ Wr, const float* __restrict__ br,
    float* __restrict__ h, float* __restrict__ partials, int n_nodes)
{
    __shared__ float sW[64 * 64];
    __shared__ float sWr[64 * 64];
    __shared__ float sb[64];
    __shared__ float sbr[64];
    __shared__ float srow[4][2][64];
    __shared__ float ssum[128];

    for (int i = threadIdx.x; i < 4096; i += 256) { sW[i] = W[i]; sWr[i] = Wr[i]; }
    if (threadIdx.x < 64)  { sb[threadIdx.x] = b[threadIdx.x]; sbr[threadIdx.x] = br[threadIdx.x]; }
    if (threadIdx.x < 128) ssum[threadIdx.x] = 0.f;
    __syncthreads();

    const int wave = threadIdx.x >> 6;
    const int lane = threadIdx.x & 63;
    float lsum = 0.f, lsq = 0.f;

    for (int n = blockIdx.x * 4 + wave; n < n_nodes; n += MV_BLOCKS * 4) {
        const int beg = __builtin_amdgcn_readfirstlane(offs[n]);
        const int end = __builtin_amdgcn_readfirstlane(offs[n + 1]);
        const float f = feats[(size_t)n * 64 + lane];    // residual row (issue early)

        // gather-sum incoming rows, 4-way unrolled for MLP
        float a0 = 0.f, a1 = 0.f, a2 = 0.f, a3 = 0.f;
        int j = beg;
        for (; j + 4 <= end; j += 4) {
            int s0 = sorted_src[j], s1 = sorted_src[j + 1];
            int s2 = sorted_src[j + 2], s3 = sorted_src[j + 3];
            a0 += feats[(size_t)s0 * 64 + lane];
            a1 += feats[(size_t)s1 * 64 + lane];
            a2 += feats[(size_t)s2 * 64 + lane];
            a3 += feats[(size_t)s3 * 64 + lane];
        }
        for (; j < end; ++j) a0 += feats[(size_t)sorted_src[j] * 64 + lane];
        const float a = (a0 + a1) + (a2 + a3);

        // matvec via LDS broadcast (same-wave ds_write->ds_read)
        srow[wave][0][lane] = a;
        srow[wave][1][lane] = f;
        float acc1 = sb[lane];
        float acc2 = sbr[lane];
        #pragma unroll
        for (int i0 = 0; i0 < 64; i0 += 4) {
            float4 a4 = *(const float4*)&srow[wave][0][i0];
            float4 f4 = *(const float4*)&srow[wave][1][i0];
            acc1 += a4.x * sW [(i0 + 0) * 64 + lane];  acc2 += f4.x * sWr[(i0 + 0) * 64 + lane];
            acc1 += a4.y * sW [(i0 + 1) * 64 + lane];  acc2 += f4.y * sWr[(i0 + 1) * 64 + lane];
            acc1 += a4.z * sW [(i0 + 2) * 64 + lane];  acc2 += f4.z * sWr[(i0 + 2) * 64 + lane];
            acc1 += a4.w * sW [(i0 + 3) * 64 + lane];  acc2 += f4.w * sWr[(i0 + 3) * 64 + lane];
        }
        const float hv = fmaxf(acc1, 0.f) + fmaxf(acc2, 0.f);
        h[(size_t)n * 64 + lane] = hv;
        lsum += hv;
        lsq  += hv * hv;
    }

    atomicAdd(&ssum[lane], lsum);
    atomicAdd(&ssum[64 + lane], lsq);
    __syncthreads();
    if (threadIdx.x < 128)
        partials[(size_t)blockIdx.x * 128 + threadIdx.x] = ssum[threadIdx.x];
}

// ---- BN stats finalize ----
__global__ __launch_bounds__(128) void k_bnstats(
    const float* __restrict__ partials, const float* __restrict__ gamma,
    const float* __restrict__ beta, float* __restrict__ scaleshift, int n_nodes)
{
    const int t = threadIdx.x;   // 0..127
    float s = 0.f;
    for (int blk = 0; blk < MV_BLOCKS; blk++) s += partials[(size_t)blk * 128 + t];
    __shared__ float red[128];
    red[t] = s;
    __syncthreads();
    if (t < 64) {
        float mean = red[t] / (float)n_nodes;
        float var  = red[64 + t] / (float)n_nodes - mean * mean;  // biased
        float sc = gamma[t] * rsqrtf(var + 1e-5f);
        scaleshift[t]      = sc;
        scaleshift[64 + t] = beta[t] - mean * sc;
    }
}

// ---- BN apply (in-place on d_out) ----
__global__ __launch_bounds__(256) void k_bnapply(
    float* __restrict__ h, const float* __restrict__ scaleshift, int total4)
{
    __shared__ float ssc[64], ssh[64];
    if (threadIdx.x < 64) {
        ssc[threadIdx.x] = scaleshift[threadIdx.x];
        ssh[threadIdx.x] = scaleshift[64 + threadIdx.x];
    }
    __syncthreads();
    for (int i = blockIdx.x * blockDim.x + threadIdx.x; i < total4;
         i += gridDim.x * blockDim.x) {
        float4 v = ((float4*)h)[i];
        const int j = (i & 15) << 2;   // 16 float4 per 64-feat row
        v.x = v.x * ssc[j + 0] + ssh[j + 0];
        v.y = v.y * ssc[j + 1] + ssh[j + 1];
        v.z = v.z * ssc[j + 2] + ssh[j + 2];
        v.w = v.w * ssc[j + 3] + ssh[j + 3];
        ((float4*)h)[i] = v;
    }
}

extern "C" void kernel_launch(void* const* d_in, const int* in_sizes, int n_in,
                              void* d_out, int out_size, void* d_ws, size_t ws_size,
                              hipStream_t stream)
{
    const float* feats = (const float*)d_in[0];
    const int*   src   = (const int*)  d_in[1];
    const int*   dst   = (const int*)  d_in[2];
    const float* W     = (const float*)d_in[3];
    const float* b     = (const float*)d_in[4];
    const float* Wr    = (const float*)d_in[5];
    const float* br    = (const float*)d_in[6];
    const float* gamma = (const float*)d_in[7];
    const float* beta  = (const float*)d_in[8];

    const int n_nodes = in_sizes[0] / 64;
    const int n_edges = in_sizes[1];
    const int nb = (n_nodes + 255) / 256;   // scan blocks (391 for N=100k; must be <=512)

    // workspace: cnt[N] | offs[N+1] | cursor[N] | bsum[512] | sorted_src[E] |
    //            partials[MV_BLOCKS*128] | scaleshift[128]   (~8.2 MB)
    int* cnt        = (int*)d_ws;
    int* offs       = cnt + n_nodes;
    int* cursor     = offs + n_nodes + 1;
    int* bsum       = cursor + n_nodes;
    int* sorted_src = bsum + 512;
    float* partials   = (float*)(sorted_src + n_edges);
    float* scaleshift = partials + (size_t)MV_BLOCKS * 128;
    float* h          = (float*)d_out;

    hipMemsetAsync(cnt, 0, (size_t)n_nodes * sizeof(int), stream);

    k_hist <<<2048, 256, 0, stream>>>(dst, cnt, n_edges);
    k_scan1<<<nb,   256, 0, stream>>>(cnt, offs, bsum, n_nodes);
    k_scan2<<<1,    512, 0, stream>>>(bsum, nb);
    k_scan3<<<nb,   256, 0, stream>>>(offs, bsum, cursor, n_nodes, n_edges);
    k_build<<<2048, 256, 0, stream>>>(src, dst, cursor, sorted_src, n_edges);
    k_gather_mv<<<MV_BLOCKS, 256, 0, stream>>>(feats, offs, sorted_src,
                                               W, b, Wr, br, h, partials, n_nodes);
    k_bnstats<<<1, 128, 0, stream>>>(partials, gamma, beta, scaleshift, n_nodes);
    k_bnapply<<<2048, 256, 0, stream>>>(h, scaleshift, n_nodes * 16);
}

// Round 3
// 312.098 us; speedup vs baseline: 1.4387x; 1.2486x over previous
//
#include <hip/hip_runtime.h>
#include <hip/hip_bf16.h>

// GCN layer: agg = segment_sum(feats[src], dst); h = relu(agg@W+b) + relu(feats@Wr+br);
// out = batchnorm(h) over node dim (biased var, eps=1e-5) * gamma + beta.
// N=100000 nodes, E=1600000 edges, F=64.
//
// R3: bf16 data plane (halves gather traffic), split gather (no-LDS, high-occupancy,
// 2 edges/iter) from MFMA-based dual matvec (kills the DS-broadcast bottleneck).
// agg lives in d_out and is overwritten in-place by h (each wave reads its own
// rows before storing them).

typedef __attribute__((ext_vector_type(8))) short short8;
typedef __attribute__((ext_vector_type(4))) float f32x4;

static __device__ __forceinline__ float bfbits_lo(unsigned u) {
    union { unsigned u; float f; } c; c.u = u << 16; return c.f;
}
static __device__ __forceinline__ float bfbits_hi(unsigned u) {
    union { unsigned u; float f; } c; c.u = u & 0xffff0000u; return c.f;
}
static __device__ __forceinline__ short bf16r(float x) {
    __hip_bfloat16 h = __float2bfloat16(x);   // RNE
    union { __hip_bfloat16 h; short s; } c; c.h = h; return c.s;
}

// ---- cast feats fp32 -> bf16 (row-major [N][64]) ----
__global__ __launch_bounds__(256) void k_cast(const float* __restrict__ in,
                                              unsigned short* __restrict__ out, int total8)
{
    for (int i = blockIdx.x * blockDim.x + threadIdx.x; i < total8;
         i += gridDim.x * blockDim.x) {
        float4 v0 = ((const float4*)in)[i * 2];
        float4 v1 = ((const float4*)in)[i * 2 + 1];
        short8 o;
        o[0] = bf16r(v0.x); o[1] = bf16r(v0.y); o[2] = bf16r(v0.z); o[3] = bf16r(v0.w);
        o[4] = bf16r(v1.x); o[5] = bf16r(v1.y); o[6] = bf16r(v1.z); o[7] = bf16r(v1.w);
        ((short8*)out)[i] = o;
    }
}

// ---- histogram of dst ----
__global__ __launch_bounds__(256) void k_hist(const int* __restrict__ dst,
                                              int* __restrict__ cnt, int n_edges)
{
    for (int e = blockIdx.x * blockDim.x + threadIdx.x; e < n_edges;
         e += gridDim.x * blockDim.x)
        atomicAdd(&cnt[dst[e]], 1);
}

// ---- scan (3 passes) ----
__global__ __launch_bounds__(256) void k_scan1(const int* __restrict__ cnt,
                                               int* __restrict__ offs,
                                               int* __restrict__ bsum, int n)
{
    __shared__ int s[256];
    const int t = threadIdx.x;
    const int gid = blockIdx.x * 256 + t;
    int v = (gid < n) ? cnt[gid] : 0;
    s[t] = v;
    __syncthreads();
    for (int off = 1; off < 256; off <<= 1) {
        int x = (t >= off) ? s[t - off] : 0;
        __syncthreads();
        if (t >= off) s[t] += x;
        __syncthreads();
    }
    if (gid < n) offs[gid] = s[t] - v;
    if (t == 255) bsum[blockIdx.x] = s[255];
}

__global__ __launch_bounds__(512) void k_scan2(int* __restrict__ bsum, int nb)
{
    __shared__ int s[512];
    const int t = threadIdx.x;
    int v = (t < nb) ? bsum[t] : 0;
    s[t] = v;
    __syncthreads();
    for (int off = 1; off < 512; off <<= 1) {
        int x = (t >= off) ? s[t - off] : 0;
        __syncthreads();
        if (t >= off) s[t] += x;
        __syncthreads();
    }
    if (t < nb) bsum[t] = s[t] - v;
}

__global__ __launch_bounds__(256) void k_scan3(int* __restrict__ offs,
                                               const int* __restrict__ bsum,
                                               int* __restrict__ cursor,
                                               int n, int n_edges)
{
    const int gid = blockIdx.x * 256 + threadIdx.x;
    if (gid < n) {
        int o = offs[gid] + bsum[blockIdx.x];
        offs[gid] = o;
        cursor[gid] = o;
    }
    if (gid == n) offs[n] = n_edges;
}

// ---- CSR build ----
__global__ __launch_bounds__(256) void k_build(const int* __restrict__ src,
                                               const int* __restrict__ dst,
                                               int* __restrict__ cursor,
                                               int* __restrict__ sorted_src, int n_edges)
{
    for (int e = blockIdx.x * blockDim.x + threadIdx.x; e < n_edges;
         e += gridDim.x * blockDim.x) {
        int pos = atomicAdd(&cursor[dst[e]], 1);
        sorted_src[pos] = src[e];
    }
}

// ---- gather-sum (bf16 rows, 2 edges/iter, fp32 accum) -> agg fp32 (in d_out) ----
__global__ __launch_bounds__(256) void k_gather(
    const unsigned short* __restrict__ feats_h, const int* __restrict__ offs,
    const int* __restrict__ sorted_src, float* __restrict__ agg, int n_nodes)
{
    const int wave = threadIdx.x >> 6;
    const int lane = threadIdx.x & 63;
    const int n = blockIdx.x * 4 + wave;
    if (n >= n_nodes) return;
    const int beg = offs[n];
    const int end = offs[n + 1];
    const int half = lane >> 5;       // 0: even edges, 1: odd edges
    const int li   = lane & 31;       // bf16x2 slot -> feats 2*li, 2*li+1

    float ax0 = 0.f, ay0 = 0.f, ax1 = 0.f, ay1 = 0.f;
    float ax2 = 0.f, ay2 = 0.f, ax3 = 0.f, ay3 = 0.f;
    int base = beg;
    for (; base + 8 <= end; base += 8) {
        const int e = base + half;
        const unsigned s0 = (unsigned)sorted_src[e];
        const unsigned s1 = (unsigned)sorted_src[e + 2];
        const unsigned s2 = (unsigned)sorted_src[e + 4];
        const unsigned s3 = (unsigned)sorted_src[e + 6];
        const unsigned v0 = *(const unsigned*)(feats_h + (size_t)s0 * 64 + li * 2);
        const unsigned v1 = *(const unsigned*)(feats_h + (size_t)s1 * 64 + li * 2);
        const unsigned v2 = *(const unsigned*)(feats_h + (size_t)s2 * 64 + li * 2);
        const unsigned v3 = *(const unsigned*)(feats_h + (size_t)s3 * 64 + li * 2);
        ax0 += bfbits_lo(v0); ay0 += bfbits_hi(v0);
        ax1 += bfbits_lo(v1); ay1 += bfbits_hi(v1);
        ax2 += bfbits_lo(v2); ay2 += bfbits_hi(v2);
        ax3 += bfbits_lo(v3); ay3 += bfbits_hi(v3);
    }
    for (; base + 2 <= end; base += 2) {
        const int e = base + half;
        const unsigned s = (unsigned)sorted_src[e];
        const unsigned v = *(const unsigned*)(feats_h + (size_t)s * 64 + li * 2);
        ax0 += bfbits_lo(v); ay0 += bfbits_hi(v);
    }
    if (base < end && half == 0) {    // odd leftover edge: even-half only
        const unsigned s = (unsigned)sorted_src[base];
        const unsigned v = *(const unsigned*)(feats_h + (size_t)s * 64 + li * 2);
        ax1 += bfbits_lo(v); ay1 += bfbits_hi(v);
    }
    float ax = (ax0 + ax1) + (ax2 + ax3);
    float ay = (ay0 + ay1) + (ay2 + ay3);
    ax += __shfl_xor(ax, 32);
    ay += __shfl_xor(ay, 32);
    if (half == 0) {
        float2 o; o.x = ax; o.y = ay;
        *(float2*)(agg + (size_t)n * 64 + li * 2) = o;
    }
}

// ---- pack W/Wr into MFMA B-fragment layout ----
// packed[((s*4+t)*64 + lane)*8 + j] = W[(s*32 + (lane>>4)*8 + j)*64 + (t*16 + (lane&15))]
__global__ __launch_bounds__(256) void k_prepW(const float* __restrict__ W,
                                               const float* __restrict__ Wr,
                                               short* __restrict__ Wpk,
                                               short* __restrict__ Wrpk)
{
    for (int idx = threadIdx.x; idx < 8192; idx += 256) {
        const int m = idx >> 12;          // 0: W, 1: Wr
        const int rem = idx & 4095;
        const int j = rem & 7;
        const int q = rem >> 3;
        const int lane = q & 63;
        const int st = q >> 6;            // 0..7
        const int s = st >> 2;
        const int t = st & 3;
        const int k = s * 32 + (lane >> 4) * 8 + j;
        const int n = t * 16 + (lane & 15);
        const float v = (m == 0) ? W[k * 64 + n] : Wr[k * 64 + n];
        short* out = (m == 0) ? Wpk : Wrpk;
        out[rem] = bf16r(v);
    }
}

// ---- dual matvec via MFMA + relu + residual + BN partial accumulation ----
// 512 threads = 8 waves; wave w: 16 rows. Block: 128 rows. In-place agg->h on d_out.
__global__ __launch_bounds__(512) void k_mv(
    const float* __restrict__ agg, const unsigned short* __restrict__ feats_h,
    const short* __restrict__ Wpk, const short* __restrict__ Wrpk,
    const float* __restrict__ b, const float* __restrict__ br,
    float* __restrict__ h, float* __restrict__ bnacc, int n_nodes)
{
    __shared__ float ssum[64], ssq[64];
    const int tid = threadIdx.x;
    const int wave = tid >> 6;
    const int lane = tid & 63;
    if (tid < 64) { ssum[tid] = 0.f; ssq[tid] = 0.f; }
    __syncthreads();

    short8 wf[8], wrf[8];
    #pragma unroll
    for (int i = 0; i < 8; i++) {
        wf[i]  = *(const short8*)(Wpk  + (i * 64 + lane) * 8);
        wrf[i] = *(const short8*)(Wrpk + (i * 64 + lane) * 8);
    }
    float bt[4], brt[4];
    #pragma unroll
    for (int t = 0; t < 4; t++) {
        bt[t]  = b [t * 16 + (lane & 15)];
        brt[t] = br[t * 16 + (lane & 15)];
    }

    const int r0 = blockIdx.x * 128 + wave * 16;
    int arow = r0 + (lane & 15);
    if (arow >= n_nodes) arow = n_nodes - 1;   // clamped rows feed masked-out outputs
    const int kb = (lane >> 4) * 8;

    short8 aggA[2], feaA[2];
    #pragma unroll
    for (int s = 0; s < 2; s++) {
        const float* ap = agg + (size_t)arow * 64 + s * 32 + kb;
        float4 v0 = *(const float4*)ap;
        float4 v1 = *(const float4*)(ap + 4);
        short8 a;
        a[0] = bf16r(v0.x); a[1] = bf16r(v0.y); a[2] = bf16r(v0.z); a[3] = bf16r(v0.w);
        a[4] = bf16r(v1.x); a[5] = bf16r(v1.y); a[6] = bf16r(v1.z); a[7] = bf16r(v1.w);
        aggA[s] = a;
        feaA[s] = *(const short8*)(feats_h + (size_t)arow * 64 + s * 32 + kb);
    }

    #pragma unroll
    for (int t = 0; t < 4; t++) {
        f32x4 c1 = {0.f, 0.f, 0.f, 0.f};
        f32x4 c2 = {0.f, 0.f, 0.f, 0.f};
        c1 = __builtin_amdgcn_mfma_f32_16x16x32_bf16(aggA[0], wf [t],     c1, 0, 0, 0);
        c1 = __builtin_amdgcn_mfma_f32_16x16x32_bf16(aggA[1], wf [4 + t], c1, 0, 0, 0);
        c2 = __builtin_amdgcn_mfma_f32_16x16x32_bf16(feaA[0], wrf[t],     c2, 0, 0, 0);
        c2 = __builtin_amdgcn_mfma_f32_16x16x32_bf16(feaA[1], wrf[4 + t], c2, 0, 0, 0);
        const int col = t * 16 + (lane & 15);
        float ls = 0.f, lq = 0.f;
        #pragma unroll
        for (int r = 0; r < 4; r++) {
            const int row = r0 + (lane >> 4) * 4 + r;
            const float hv = fmaxf(c1[r] + bt[t], 0.f) + fmaxf(c2[r] + brt[t], 0.f);
            if (row < n_nodes) {
                h[(size_t)row * 64 + col] = hv;
                ls += hv;
                lq += hv * hv;
            }
        }
        ls += __shfl_xor(ls, 16); ls += __shfl_xor(ls, 32);
        lq += __shfl_xor(lq, 16); lq += __shfl_xor(lq, 32);
        if ((lane >> 4) == 0) {
            atomicAdd(&ssum[col], ls);
            atomicAdd(&ssq[col], lq);
        }
    }
    __syncthreads();
    if (tid < 64) {
        atomicAdd(&bnacc[tid], ssum[tid]);
        atomicAdd(&bnacc[64 + tid], ssq[tid]);
    }
}

// ---- BN scale/shift from accumulated stats ----
__global__ __launch_bounds__(64) void k_bnscale(
    const float* __restrict__ bnacc, const float* __restrict__ gamma,
    const float* __restrict__ beta, float* __restrict__ scaleshift, int n_nodes)
{
    const int t = threadIdx.x;
    const float inv_n = 1.f / (float)n_nodes;
    const float mean = bnacc[t] * inv_n;
    const float var  = bnacc[64 + t] * inv_n - mean * mean;  // biased
    const float sc = gamma[t] * rsqrtf(var + 1e-5f);
    scaleshift[t]      = sc;
    scaleshift[64 + t] = beta[t] - mean * sc;
}

// ---- BN apply in-place ----
__global__ __launch_bounds__(256) void k_bnapply(
    float* __restrict__ h, const float* __restrict__ scaleshift, int total4)
{
    __shared__ float ssc[64], ssh[64];
    if (threadIdx.x < 64) {
        ssc[threadIdx.x] = scaleshift[threadIdx.x];
        ssh[threadIdx.x] = scaleshift[64 + threadIdx.x];
    }
    __syncthreads();
    for (int i = blockIdx.x * blockDim.x + threadIdx.x; i < total4;
         i += gridDim.x * blockDim.x) {
        float4 v = ((float4*)h)[i];
        const int j = (i & 15) << 2;
        v.x = v.x * ssc[j + 0] + ssh[j + 0];
        v.y = v.y * ssc[j + 1] + ssh[j + 1];
        v.z = v.z * ssc[j + 2] + ssh[j + 2];
        v.w = v.w * ssc[j + 3] + ssh[j + 3];
        ((float4*)h)[i] = v;
    }
}

extern "C" void kernel_launch(void* const* d_in, const int* in_sizes, int n_in,
                              void* d_out, int out_size, void* d_ws, size_t ws_size,
                              hipStream_t stream)
{
    const float* feats = (const float*)d_in[0];
    const int*   src   = (const int*)  d_in[1];
    const int*   dst   = (const int*)  d_in[2];
    const float* W     = (const float*)d_in[3];
    const float* b     = (const float*)d_in[4];
    const float* Wr    = (const float*)d_in[5];
    const float* br    = (const float*)d_in[6];
    const float* gamma = (const float*)d_in[7];
    const float* beta  = (const float*)d_in[8];

    const int n_nodes = in_sizes[0] / 64;
    const int n_edges = in_sizes[1];
    const int nb = (n_nodes + 255) / 256;      // <=512

    // ws layout (4B units): cnt[N] | bnacc[128] | offs[N+1] | cursor[N] | bsum[512] |
    //   sorted_src[E] | feats_h[N*64 u16] | Wpk[4096 s16] | Wrpk[4096 s16] | scaleshift[128]
    int*   cnt        = (int*)d_ws;
    float* bnacc      = (float*)(cnt + n_nodes);
    int*   offs       = (int*)(bnacc + 128);
    int*   cursor     = offs + n_nodes + 1;
    int*   bsum       = cursor + n_nodes;
    int*   sorted_src = bsum + 512;
    unsigned short* feats_h = (unsigned short*)(sorted_src + n_edges);
    short* Wpk        = (short*)(feats_h + (size_t)n_nodes * 64);
    short* Wrpk       = Wpk + 4096;
    float* scaleshift = (float*)(Wrpk + 4096);
    float* agg        = (float*)d_out;         // in-place: agg -> h -> bn
    float* h          = (float*)d_out;

    // zero cnt + bnacc in one shot (contiguous)
    hipMemsetAsync(cnt, 0, (size_t)(n_nodes + 128) * sizeof(int), stream);

    k_cast <<<2048, 256, 0, stream>>>(feats, feats_h, n_nodes * 8);
    k_prepW<<<1,    256, 0, stream>>>(W, Wr, Wpk, Wrpk);
    k_hist <<<2048, 256, 0, stream>>>(dst, cnt, n_edges);
    k_scan1<<<nb,   256, 0, stream>>>(cnt, offs, bsum, n_nodes);
    k_scan2<<<1,    512, 0, stream>>>(bsum, nb);
    k_scan3<<<nb,   256, 0, stream>>>(offs, bsum, cursor, n_nodes, n_edges);
    k_build<<<2048, 256, 0, stream>>>(src, dst, cursor, sorted_src, n_edges);
    k_gather<<<(n_nodes + 3) / 4, 256, 0, stream>>>(feats_h, offs, sorted_src, agg, n_nodes);
    k_mv   <<<(n_nodes + 127) / 128, 512, 0, stream>>>(agg, feats_h, Wpk, Wrpk,
                                                       b, br, h, bnacc, n_nodes);
    k_bnscale<<<1, 64, 0, stream>>>(bnacc, gamma, beta, scaleshift, n_nodes);
    k_bnapply<<<2048, 256, 0, stream>>>(h, scaleshift, n_nodes * 16);
}